// Round 6
// baseline (1508.645 us; speedup 1.0000x reference)
//
#include <hip/hip_runtime.h>
#include <hip/hip_cooperative_groups.h>
#include <math.h>

namespace cg = cooperative_groups;

// Problem constants (B,C,H,W fixed by reference)
constexpr int B = 2, C = 256, H = 512, W = 512, P = 32;
constexpr int NR = H / P;      // 16
constexpr int NC = W / P;      // 16
constexpr int NPOS = NR * NC;  // 256
constexpr float EPS = 1e-5f;

constexpr int GRID = 1024;     // 4 blocks/CU x 256 CUs; co-resident for grid.sync

typedef float floatx4 __attribute__((ext_vector_type(4)));

__device__ inline float gelu_exact(float x) {
    return 0.5f * x * (1.0f + erff(x * 0.70710678118654752440f));
}

// ---------------------------------------------------------------------------
// One cooperative kernel, 4 phases separated by grid.sync():
//  P1 pool:   8192 strips (32x512) -> xp[b,p,c] position-major (537 MB read)
//  P2 stats:  per-position channel mean/rsqrt (blocks 0..511)
//     pwt:    transpose pw_w into [c4][o] float4 blocked layout (blocks 512..575)
//  P3 fused:  norm -> dw3x3+bias -> GELU -> pw 1x1+bias -> z[b,p,c]
//  P4 up:     broadcast 16x16 -> 512x512 splat writes (537 MB write)
// Small tensors (xp 512K, z 512K, mu/rs 4K, pw_t 256K) stay L2/L3-resident.
// ---------------------------------------------------------------------------
__global__ __launch_bounds__(256, 4) void mega_kernel(
    const float* __restrict__ h_past,
    const float* __restrict__ scale, const float* __restrict__ shift,
    const float* __restrict__ dw_w, const float* __restrict__ dw_b,
    const float* __restrict__ pw_w, const float* __restrict__ pw_b,
    float* __restrict__ xp, float* __restrict__ z,
    float* __restrict__ mu_arr, float* __restrict__ rs_arr,
    floatx4* __restrict__ pw_t,
    floatx4* __restrict__ out)
{
    cg::grid_group grid = cg::this_grid();
    const int t = threadIdx.x;
    const int bid = blockIdx.x;
    __shared__ float sm[256];
    __shared__ float red[8];

    // ---- Phase 1: pool (8 strips per block) ----
    {
        int f4 = t & 127;        // float4 index within a row (128 per row)
        int row0 = t >> 7;       // 0 or 1
        for (int i = 0; i < 8; ++i) {
            int s = bid * 8 + i;
            int br = s & 15;
            int c  = (s >> 4) & 255;
            int b  = s >> 12;
            const floatx4* src = (const floatx4*)(
                h_past + (((size_t)(b * C + c)) * H + (size_t)br * P) * W);
            float acc = 0.f;
#pragma unroll
            for (int k = 0; k < 16; ++k) {
                floatx4 v = src[(row0 + 2 * k) * 128 + f4];
                acc += v.x + v.y + v.z + v.w;
            }
            sm[t] = acc;
            __syncthreads();
            if (t < 16) {
                float a2 = 0.f;
#pragma unroll
                for (int j = 0; j < 8; ++j)
                    a2 += sm[t * 8 + j] + sm[128 + t * 8 + j];
                xp[((size_t)(b * NPOS + br * NC + t)) * C + c] = a2 * (1.0f / (P * P));
            }
            __syncthreads();
        }
    }
    __threadfence();
    grid.sync();

    // ---- Phase 2: stats (blocks 0..511) | pw transpose (blocks 512..575) ----
    if (bid < B * NPOS) {
        float v = xp[(size_t)bid * C + t];
        float s = v;
#pragma unroll
        for (int off = 32; off > 0; off >>= 1) s += __shfl_down(s, off, 64);
        int wave = t >> 6, lane = t & 63;
        if (lane == 0) red[wave] = s;
        __syncthreads();
        float mu = (red[0] + red[1] + red[2] + red[3]) * (1.0f / C);
        float d = v - mu;
        float s2 = d * d;
#pragma unroll
        for (int off = 32; off > 0; off >>= 1) s2 += __shfl_down(s2, off, 64);
        if (lane == 0) red[4 + wave] = s2;
        __syncthreads();
        if (t == 0) {
            float var = (red[4] + red[5] + red[6] + red[7]) * (1.0f / C);
            mu_arr[bid] = mu;
            rs_arr[bid] = rsqrtf(var + EPS);
        }
    } else if (bid < B * NPOS + 64) {
        int idx = (bid - B * NPOS) * 256 + t;   // 64 blocks x 256 = 16384 float4
        int c4 = idx >> 8;
        int o  = idx & 255;
        const float* srcw = pw_w + o * C + 4 * c4;
        floatx4 v = {srcw[0], srcw[1], srcw[2], srcw[3]};
        pw_t[idx] = v;
    }
    __threadfence();
    grid.sync();

    // ---- Phase 3: norm -> dw3x3 -> GELU -> pw (blocks 0..511) ----
    if (bid < B * NPOS) {
        int p = bid & 255;
        int b = bid >> 8;
        int h = p >> 4;
        int w = p & 15;
        int c = t;
        float sc = scale[c];
        float sh = shift[c];
        const float* wt  = dw_w + c * 9;
        const float* xpb = xp + (size_t)b * NPOS * C;
        const float* mub = mu_arr + b * NPOS;
        const float* rsb = rs_arr + b * NPOS;
        float acc = 0.f;
#pragma unroll
        for (int kh = 0; kh < 3; ++kh) {
            int hh = h + kh - 1;
            if (hh < 0 || hh >= NR) continue;
#pragma unroll
            for (int kw = 0; kw < 3; ++kw) {
                int ww = w + kw - 1;
                if (ww < 0 || ww >= NC) continue;
                int q = hh * NC + ww;
                float xv = xpb[(size_t)q * C + c];            // coalesced
                float xn = (xv - mub[q]) * rsb[q] * sc + sh;  // broadcast stats
                acc += xn * wt[kh * 3 + kw];
            }
        }
        float yv = gelu_exact(acc + dw_b[c]);
        sm[c] = yv;
        __syncthreads();
        const floatx4* yv4 = (const floatx4*)sm;
        float acc2 = 0.f;
#pragma unroll 4
        for (int c4 = 0; c4 < 64; ++c4) {
            floatx4 wv = pw_t[c4 * 256 + c];   // coalesced over out-channel c
            floatx4 vv = yv4[c4];              // LDS broadcast
            acc2 += wv.x * vv.x + wv.y * vv.y + wv.z * vv.z + wv.w * vv.w;
        }
        z[(size_t)bid * C + c] = acc2 + pw_b[c];  // coalesced
    }
    __threadfence();
    grid.sync();

    // ---- Phase 4: broadcast upsample (all blocks, grid-stride) ----
    {
        const int total = B * C * H * (W / 4);  // 33,554,432 float4
        for (int idx = bid * 256 + t; idx < total; idx += GRID * 256) {
            int w4 = idx & 127;          // W/4 = 128
            int h  = (idx >> 7) & 511;
            int bc = idx >> 16;          // b*C + c
            int b  = bc >> 8;
            int c  = bc & 255;
            int p  = (h >> 5) * NC + (w4 >> 3);
            float v = z[((size_t)(b * NPOS + p)) * C + c];
            floatx4 o = {v, v, v, v};
            out[idx] = o;
        }
    }
}

extern "C" void kernel_launch(void* const* d_in, const int* in_sizes, int n_in,
                              void* d_out, int out_size, void* d_ws, size_t ws_size,
                              hipStream_t stream) {
    const float* h_past = (const float*)d_in[0];
    const float* scale  = (const float*)d_in[1];
    const float* shift  = (const float*)d_in[2];
    const float* dw_w   = (const float*)d_in[3];
    const float* dw_b   = (const float*)d_in[4];
    const float* pw_w   = (const float*)d_in[5];
    const float* pw_b   = (const float*)d_in[6];
    float* out = (float*)d_out;

    float* ws = (float*)d_ws;
    const int SMALL = B * C * NPOS;  // 131072 elements
    float* xp = ws;                        // [b, p, c]
    float* z  = ws + SMALL;                // [b, p, c]
    float* mu = ws + 2 * SMALL;            // [b*NPOS]
    float* rs = mu + B * NPOS;             // [b*NPOS]
    floatx4* pw_t = (floatx4*)(rs + B * NPOS);  // 16384 float4 (256 KB)
    floatx4* outv = (floatx4*)out;

    void* args[] = {
        (void*)&h_past, (void*)&scale, (void*)&shift,
        (void*)&dw_w, (void*)&dw_b, (void*)&pw_w, (void*)&pw_b,
        (void*)&xp, (void*)&z, (void*)&mu, (void*)&rs,
        (void*)&pw_t, (void*)&outv,
    };
    hipLaunchCooperativeKernel((const void*)mega_kernel, dim3(GRID), dim3(256),
                               args, 0, stream);
}